// Round 7
// baseline (3508.183 us; speedup 1.0000x reference)
//
#include <hip/hip_runtime.h>
#include <math.h>

#define N_NODES 100000
#define N_EDGES 1600000
#define RREL 4
#define DDIM 128
#define KDIM 512      // RREL*DDIM
#define NKEY 400000   // N_NODES*RREL
#define SROW 524      // f32 per LDS node-row (512 + 12 pad; 12*l15 mod 32 -> 2-way max on b128 reads)

typedef __bf16 bf16x8 __attribute__((ext_vector_type(8)));
typedef float f32x4 __attribute__((ext_vector_type(4)));

__device__ __forceinline__ float bflo(unsigned u){ return __builtin_bit_cast(float, u << 16); }
__device__ __forceinline__ float bfhi(unsigned u){ return __builtin_bit_cast(float, u & 0xffff0000u); }
__device__ __forceinline__ unsigned f2bf(float f){
  unsigned u = __builtin_bit_cast(unsigned, f);
  return (u + 0x7fffu + ((u >> 16) & 1u)) >> 16;   // RNE, finite inputs
}
__device__ __forceinline__ int iclamp(int v, int lo, int hi){
  return v < lo ? lo : (v > hi ? hi : v);
}

// ---------------- counting sort of edges by key = dst*4 + et ----------------

__global__ void hist_kernel(const int* __restrict__ dst, const int* __restrict__ et,
                            int* __restrict__ counts){
  int e = blockIdx.x * 256 + threadIdx.x;
  int key = iclamp(dst[e] * RREL + et[e], 0, NKEY - 1);
  atomicAdd(&counts[key], 1);
}

__global__ void scan_local(const int* __restrict__ in, int* __restrict__ out,
                           int* __restrict__ bsums, int K){
  __shared__ int s[1024];
  int t = threadIdx.x;
  int i = blockIdx.x * 1024 + t;
  int v = (i < K) ? in[i] : 0;
  s[t] = v; __syncthreads();
  for (int off = 1; off < 1024; off <<= 1){
    int x = (t >= off) ? s[t - off] : 0;
    __syncthreads();
    s[t] += x;
    __syncthreads();
  }
  if (i < K) out[i] = s[t] - v;           // exclusive within block
  if (t == 1023) bsums[blockIdx.x] = s[t];
}

__global__ void scan_sums(int* __restrict__ b, int nb){
  __shared__ int s[1024];
  int t = threadIdx.x;
  int v = (t < nb) ? b[t] : 0;
  s[t] = v; __syncthreads();
  for (int off = 1; off < 1024; off <<= 1){
    int x = (t >= off) ? s[t - off] : 0;
    __syncthreads();
    s[t] += x;
    __syncthreads();
  }
  if (t < nb) b[t] = s[t] - v;            // exclusive block prefix
}

__global__ void scan_add(int* __restrict__ out, int* __restrict__ cursor,
                         const int* __restrict__ bsums, int K, int total){
  int t = threadIdx.x;
  int i = blockIdx.x * 1024 + t;
  if (i < K){
    int v = out[i] + bsums[blockIdx.x];
    out[i] = v;
    cursor[i] = v;
  }
  if (i == 0) out[K] = total;
}

// edata[p] = (src << 6) | (key & 63); block covers 64 consecutive keys.

__global__ void scatter_kernel(const int* __restrict__ src, const int* __restrict__ dst,
                               const int* __restrict__ et, int* __restrict__ cursor,
                               int* __restrict__ edata){
  int e = blockIdx.x * 256 + threadIdx.x;
  int key = iclamp(dst[e] * RREL + et[e], 0, NKEY - 1);
  int p = atomicAdd(&cursor[key], 1);
  p = iclamp(p, 0, N_EDGES - 1);
  int s = iclamp(src[e], 0, N_NODES - 1);
  edata[p] = (s << 6) | (key & 63);
}

// ---------------- x (f32 [N,128]) -> PLANAR packed bf16 [N,64] uints ----------------
// uint i of node n holds dims (i, i+64): lo = x[n][i], hi = x[n][i+64].

__global__ void convert_x(const float* __restrict__ x, unsigned* __restrict__ xb){
  int i = blockIdx.x * 256 + threadIdx.x;      // over N*64
  int n = i >> 6, d = i & 63;
  float lo = x[(size_t)n * 128 + d];
  float hi = x[(size_t)n * 128 + d + 64];
  xb[i] = f2bf(lo) | (f2bf(hi) << 16);
}

// ---------------- W (f32 [512][128]) -> Bt bf16 [128][512] ----------------

__global__ void transpose_w(const float* __restrict__ W, unsigned short* __restrict__ Bt){
  int idx = blockIdx.x * 256 + threadIdx.x;    // 65536
  int k = idx >> 7, n = idx & 127;
  Bt[n * KDIM + k] = (unsigned short)f2bf(W[idx]);
}

// ---------------- fused block kernel ----------------
// Phase A: block of 16 nodes; 4 waves split the contiguous edge range evenly. Per edge the
// wave reads the node's 256B planar row coalesced (lane owns dims lane, lane+64) and does
// two unconditional LDS atomicAdds (stride-1 addressing, branchless -> loads pipeline).
// Phase B (HEAD=0): 16x128 GEMM from LDS (natural dim order), tanh, planar bf16 store.
// Phase B (HEAD=1): dot with W3 (f32 [512][2]) + softmax, f32 store.

template<int HEAD>
__global__ __launch_bounds__(256) void fused_block(const unsigned* __restrict__ hin,
                                                   const int* __restrict__ edata,
                                                   const int* __restrict__ offs,
                                                   const __bf16* __restrict__ Bt,
                                                   const float* __restrict__ W3f,
                                                   unsigned* __restrict__ hout,
                                                   float* __restrict__ fout){
  __shared__ float sacc[16 * SROW];
  int tid = threadIdx.x;
  int w = tid >> 6, lane = tid & 63;
  int n0 = blockIdx.x * 16;
  int kbase = n0 * 4;

  for (int i = tid; i < 16 * SROW; i += 256) sacc[i] = 0.f;
  __syncthreads();

  int e0 = iclamp(offs[kbase], 0, N_EDGES);
  int e1 = iclamp(offs[kbase + 64], e0, N_EDGES);
  int per = ((e1 - e0) + 3) >> 2;
  int wb = e0 + w * per;
  int we = wb + per; if (we > e1) we = e1; if (wb > we) wb = we;

  // branchless per-edge accumulate: dims (lane, lane+64) of key kl
  auto flush = [&](int d, unsigned u){
    int kl = d & 63;
    int base = (kl >> 2) * SROW + (kl & 3) * 128 + lane;
    atomicAdd(&sacc[base], bflo(u));          // ds_add_f32, no return
    atomicAdd(&sacc[base + 64], bfhi(u));
  };

  for (int g = wb; g < we; g += 64){
    int gi = g + lane;
    int ev = (gi < we) ? edata[gi] : 0;
    int cnt = we - g; if (cnt > 64) cnt = 64;
    int j = 0;
    for (; j + 8 <= cnt; j += 8){
      int d0 = __builtin_amdgcn_readlane(ev, j + 0);
      int d1 = __builtin_amdgcn_readlane(ev, j + 1);
      int d2 = __builtin_amdgcn_readlane(ev, j + 2);
      int d3 = __builtin_amdgcn_readlane(ev, j + 3);
      int d4 = __builtin_amdgcn_readlane(ev, j + 4);
      int d5 = __builtin_amdgcn_readlane(ev, j + 5);
      int d6 = __builtin_amdgcn_readlane(ev, j + 6);
      int d7 = __builtin_amdgcn_readlane(ev, j + 7);
      unsigned u0 = hin[(size_t)(d0 >> 6) * 64 + lane];   // 8 independent row-gathers in flight
      unsigned u1 = hin[(size_t)(d1 >> 6) * 64 + lane];
      unsigned u2 = hin[(size_t)(d2 >> 6) * 64 + lane];
      unsigned u3 = hin[(size_t)(d3 >> 6) * 64 + lane];
      unsigned u4 = hin[(size_t)(d4 >> 6) * 64 + lane];
      unsigned u5 = hin[(size_t)(d5 >> 6) * 64 + lane];
      unsigned u6 = hin[(size_t)(d6 >> 6) * 64 + lane];
      unsigned u7 = hin[(size_t)(d7 >> 6) * 64 + lane];
      flush(d0, u0); flush(d1, u1); flush(d2, u2); flush(d3, u3);
      flush(d4, u4); flush(d5, u5); flush(d6, u6); flush(d7, u7);
    }
    for (; j < cnt; ++j){
      int d = __builtin_amdgcn_readlane(ev, j);
      unsigned u = hin[(size_t)(d >> 6) * 64 + lane];
      flush(d, u);
    }
  }
  __syncthreads();

  if (!HEAD){
    // ---- GEMM: C[16x128] = mean(sacc) @ B ; wave w: cols w*16+l15 and 64+w*16+l15 ----
    int l15 = lane & 15, quad = lane >> 4;
    int ob = (n0 + l15) * 4;
    int o0 = offs[ob], o1 = offs[ob + 1], o2 = offs[ob + 2], o3 = offs[ob + 3], o4 = offs[ob + 4];
    float inv[4];
    inv[0] = (o1 > o0) ? 1.f / (float)(o1 - o0) : 0.f;
    inv[1] = (o2 > o1) ? 1.f / (float)(o2 - o1) : 0.f;
    inv[2] = (o3 > o2) ? 1.f / (float)(o3 - o2) : 0.f;
    inv[3] = (o4 > o3) ? 1.f / (float)(o4 - o3) : 0.f;

    f32x4 acc0 = (f32x4){0.f,0.f,0.f,0.f};
    f32x4 acc1 = (f32x4){0.f,0.f,0.f,0.f};
    int c0 = w * 16 + l15, c1 = 64 + w * 16 + l15;
    #pragma unroll
    for (int k0 = 0; k0 < KDIM; k0 += 32){
      float sc = inv[k0 >> 7];
      const float* ap = &sacc[l15 * SROW + k0 + quad * 8];
      uint4 pv;
      pv.x = f2bf(ap[0] * sc) | (f2bf(ap[1] * sc) << 16);
      pv.y = f2bf(ap[2] * sc) | (f2bf(ap[3] * sc) << 16);
      pv.z = f2bf(ap[4] * sc) | (f2bf(ap[5] * sc) << 16);
      pv.w = f2bf(ap[6] * sc) | (f2bf(ap[7] * sc) << 16);
      bf16x8 af = __builtin_bit_cast(bf16x8, pv);
      const __bf16* bb = Bt + k0 + quad * 8;
      bf16x8 b0 = *(const bf16x8*)(bb + (size_t)c0 * KDIM);
      bf16x8 b1 = *(const bf16x8*)(bb + (size_t)c1 * KDIM);
      acc0 = __builtin_amdgcn_mfma_f32_16x16x32_bf16(af, b0, acc0, 0, 0, 0);
      acc1 = __builtin_amdgcn_mfma_f32_16x16x32_bf16(af, b1, acc1, 0, 0, 0);
    }
    // C layout: col=c (l15-mapped), row=quad*4+reg -> node n0+row; planar store
    #pragma unroll
    for (int reg = 0; reg < 4; ++reg){
      int node = n0 + quad * 4 + reg;
      unsigned pv = f2bf(tanhf(acc0[reg])) | (f2bf(tanhf(acc1[reg])) << 16);
      hout[(size_t)node * 64 + w * 16 + l15] = pv;
    }
  } else {
    // ---- head: wave w handles nodes n0+4w..+3; 16 lanes per node, dims seg+16j ----
    int nl = lane >> 4;
    int seg = lane & 15;
    int node = n0 + w * 4 + nl;
    int ob = node * 4;
    int o0 = offs[ob], o1 = offs[ob + 1], o2 = offs[ob + 2], o3 = offs[ob + 3], o4 = offs[ob + 4];
    float inv[4];
    inv[0] = (o1 > o0) ? 1.f / (float)(o1 - o0) : 0.f;
    inv[1] = (o2 > o1) ? 1.f / (float)(o2 - o1) : 0.f;
    inv[2] = (o3 > o2) ? 1.f / (float)(o3 - o2) : 0.f;
    inv[3] = (o4 > o3) ? 1.f / (float)(o4 - o3) : 0.f;

    const float* ap = &sacc[(w * 4 + nl) * SROW + seg];
    float dA = 0.f, dB = 0.f;
    #pragma unroll
    for (int j = 0; j < 32; ++j){
      float m = ap[16 * j] * inv[j >> 3];          // dim seg+16j; r = j>>3
      float2 wv = *(const float2*)(W3f + 2 * (seg + 16 * j));
      dA += m * wv.x; dB += m * wv.y;
    }
    dA += __shfl_xor(dA, 1); dB += __shfl_xor(dB, 1);
    dA += __shfl_xor(dA, 2); dB += __shfl_xor(dB, 2);
    dA += __shfl_xor(dA, 4); dB += __shfl_xor(dB, 4);
    dA += __shfl_xor(dA, 8); dB += __shfl_xor(dB, 8);
    if (seg == 0){
      float mx = fmaxf(dA, dB);
      float ea = __expf(dA - mx), eb = __expf(dB - mx);
      float invs = 1.0f / (ea + eb);
      *(float2*)(fout + 2 * node) = (float2){ea * invs, eb * invs};           // softmax [N,2]
      *(float2*)(fout + 2 * N_NODES + 2 * node) = (float2){dA, dB};           // logits  [N,2]
    }
  }
}

// ---------------- launch ----------------

extern "C" void kernel_launch(void* const* d_in, const int* in_sizes, int n_in,
                              void* d_out, int out_size, void* d_ws, size_t ws_size,
                              hipStream_t stream){
  const float* x  = (const float*)d_in[0];
  const int* ei   = (const int*)d_in[1];
  const int* et   = (const int*)d_in[2];
  const float* W1 = (const float*)d_in[3];
  const float* W2 = (const float*)d_in[4];
  const float* W3 = (const float*)d_in[5];
  float* out = (float*)d_out;
  const int* src = ei;
  const int* dst = ei + N_EDGES;

  // workspace layout: ~61 MB total
  char* p = (char*)d_ws;
  auto alloc = [&](size_t bytes) -> char* {
    char* q = p; p += (bytes + 63) & ~(size_t)63; return q;
  };
  int* counts = (int*)alloc((size_t)NKEY * 4);          // reused as cursor
  int* cursor = counts;
  int* offs   = (int*)alloc((size_t)(NKEY + 1) * 4);
  int* bsums  = (int*)alloc(1024 * 4);
  int* edata  = (int*)alloc((size_t)N_EDGES * 4);
  unsigned short* Bt = (unsigned short*)alloc((size_t)DDIM * KDIM * 2);
  unsigned* h1 = (unsigned*)alloc((size_t)N_NODES * 64 * 4);
  unsigned* h2 = (unsigned*)alloc((size_t)N_NODES * 64 * 4);
  unsigned* xb = h2;   // x-as-planar-bf16 lives in h2's slot (dead until layer-2 output)

  // sort edges by (dst, relation)
  hipMemsetAsync(counts, 0, (size_t)NKEY * 4, stream);
  hist_kernel<<<N_EDGES / 256, 256, 0, stream>>>(dst, et, counts);
  int nb = (NKEY + 1023) / 1024;  // 391
  scan_local<<<nb, 1024, 0, stream>>>(counts, offs, bsums, NKEY);
  scan_sums<<<1, 1024, 0, stream>>>(bsums, nb);
  scan_add<<<nb, 1024, 0, stream>>>(offs, cursor, bsums, NKEY, N_EDGES);
  scatter_kernel<<<N_EDGES / 256, 256, 0, stream>>>(src, dst, et, cursor, edata);

  int fgrid = N_NODES / 16;  // 6250

  // layer 1: x -> planar bf16, block agg -> @W1 -> tanh -> h1
  convert_x<<<(N_NODES * 64) / 256, 256, 0, stream>>>(x, xb);
  transpose_w<<<(DDIM * KDIM) / 256, 256, 0, stream>>>(W1, Bt);
  fused_block<0><<<fgrid, 256, 0, stream>>>(xb, edata, offs, (const __bf16*)Bt, nullptr, h1, nullptr);
  // layer 2: h1 -> h2 (xb dead from here on)
  transpose_w<<<(DDIM * KDIM) / 256, 256, 0, stream>>>(W2, Bt);
  fused_block<0><<<fgrid, 256, 0, stream>>>(h1, edata, offs, (const __bf16*)Bt, nullptr, h2, nullptr);
  // layer 3 + softmax head (f32 out)
  fused_block<1><<<fgrid, 256, 0, stream>>>(h2, edata, offs, nullptr, W3, nullptr, out);
}

// Round 8
// 1052.285 us; speedup vs baseline: 3.3339x; 3.3339x over previous
//
#include <hip/hip_runtime.h>
#include <math.h>

#define N_NODES 100000
#define N_EDGES 1600000
#define RREL 4
#define DDIM 128
#define KDIM 512      // RREL*DDIM
#define NKEY 400000   // N_NODES*RREL

typedef __bf16 bf16x8 __attribute__((ext_vector_type(8)));
typedef float f32x4 __attribute__((ext_vector_type(4)));

__device__ __forceinline__ float bflo(unsigned u){ return __builtin_bit_cast(float, u << 16); }
__device__ __forceinline__ float bfhi(unsigned u){ return __builtin_bit_cast(float, u & 0xffff0000u); }
__device__ __forceinline__ unsigned f2bf(float f){
  unsigned u = __builtin_bit_cast(unsigned, f);
  return (u + 0x7fffu + ((u >> 16) & 1u)) >> 16;   // RNE, finite inputs
}
__device__ __forceinline__ int iclamp(int v, int lo, int hi){
  return v < lo ? lo : (v > hi ? hi : v);
}

// ---------------- counting sort of edges by key = dst*4 + et ----------------

__global__ void hist_kernel(const int* __restrict__ dst, const int* __restrict__ et,
                            int* __restrict__ counts){
  int e = blockIdx.x * 256 + threadIdx.x;
  int key = iclamp(dst[e] * RREL + et[e], 0, NKEY - 1);
  atomicAdd(&counts[key], 1);
}

__global__ void scan_local(const int* __restrict__ in, int* __restrict__ out,
                           int* __restrict__ bsums, int K){
  __shared__ int s[1024];
  int t = threadIdx.x;
  int i = blockIdx.x * 1024 + t;
  int v = (i < K) ? in[i] : 0;
  s[t] = v; __syncthreads();
  for (int off = 1; off < 1024; off <<= 1){
    int x = (t >= off) ? s[t - off] : 0;
    __syncthreads();
    s[t] += x;
    __syncthreads();
  }
  if (i < K) out[i] = s[t] - v;           // exclusive within block
  if (t == 1023) bsums[blockIdx.x] = s[t];
}

__global__ void scan_sums(int* __restrict__ b, int nb){
  __shared__ int s[1024];
  int t = threadIdx.x;
  int v = (t < nb) ? b[t] : 0;
  s[t] = v; __syncthreads();
  for (int off = 1; off < 1024; off <<= 1){
    int x = (t >= off) ? s[t - off] : 0;
    __syncthreads();
    s[t] += x;
    __syncthreads();
  }
  if (t < nb) b[t] = s[t] - v;            // exclusive block prefix
}

__global__ void scan_add(int* __restrict__ out, int* __restrict__ cursor,
                         const int* __restrict__ bsums, int K, int total){
  int t = threadIdx.x;
  int i = blockIdx.x * 1024 + t;
  if (i < K){
    int v = out[i] + bsums[blockIdx.x];
    out[i] = v;
    cursor[i] = v;
  }
  if (i == 0) out[K] = total;
}

__global__ void scatter_kernel(const int* __restrict__ src, const int* __restrict__ dst,
                               const int* __restrict__ et, int* __restrict__ cursor,
                               int* __restrict__ ssrc){
  int e = blockIdx.x * 256 + threadIdx.x;
  int key = iclamp(dst[e] * RREL + et[e], 0, NKEY - 1);
  int p = atomicAdd(&cursor[key], 1);
  p = iclamp(p, 0, N_EDGES - 1);
  ssrc[p] = iclamp(src[e], 0, N_NODES - 1);
}

// ---------------- x (f32 [N,128]) -> packed bf16 pairs [N,64] uints ----------------

__global__ void convert_x(const float* __restrict__ x, unsigned* __restrict__ xb){
  int i = blockIdx.x * 256 + threadIdx.x;      // over N*64
  float2 v = *(const float2*)(x + (size_t)i * 2);
  xb[i] = f2bf(v.x) | (f2bf(v.y) << 16);
}

// ---------------- W (f32 [512][128]) -> Bt bf16 [128][512] ----------------

__global__ void transpose_w(const float* __restrict__ W, unsigned short* __restrict__ Bt){
  int idx = blockIdx.x * 256 + threadIdx.x;    // 65536
  int k = idx >> 7, n = idx & 127;
  Bt[n * KDIM + k] = (unsigned short)f2bf(W[idx]);
}

// ---------------- fused node kernel: mean -> (@W,tanh | W3-dot,softmax) ----------------
// Wave = 16 nodes; lane (l15,quad) owns node n0+l15, dims quad*8+j of each 32-K window.
// Gather: 4-edge unroll per relation -> 16 independent uint4 loads in flight per round.
// Tail edges duplicate the first row address (MSHR-merge, no extra traffic); validity and
// the 1/cnt mean scale are folded into the accumulate weight (FMA).
// HEAD=0: 4 MFMA K-steps per relation into accC, tanh epilogue, bf16 store.
// HEAD=1: per-lane dot with W3 dims, quad shfl-reduce, softmax, f32 store.

template<int HEAD>
__global__ __launch_bounds__(256, 3) void fused_node(const unsigned* __restrict__ hin,
                                                     const int* __restrict__ ssrc,
                                                     const int* __restrict__ offs,
                                                     const __bf16* __restrict__ Bt,
                                                     const float* __restrict__ W3f,
                                                     unsigned short* __restrict__ hout,
                                                     float* __restrict__ fout){
  int tid = threadIdx.x;
  int w = tid >> 6, lane = tid & 63;
  int l15 = lane & 15, quad = lane >> 4;
  int n0w = blockIdx.x * 64 + w * 16;
  int n = n0w + l15;                     // this lane's node
  int valid = (n < N_NODES);

  f32x4 accC[8];
  if (!HEAD){
    #pragma unroll
    for (int tc = 0; tc < 8; tc++) accC[tc] = (f32x4){0.f, 0.f, 0.f, 0.f};
  }
  float dA = 0.f, dB = 0.f;

  auto acc8 = [&](float* a, uint4 u, float wt){
    a[0] += bflo(u.x) * wt; a[1] += bfhi(u.x) * wt;
    a[2] += bflo(u.y) * wt; a[3] += bfhi(u.y) * wt;
    a[4] += bflo(u.z) * wt; a[5] += bfhi(u.z) * wt;
    a[6] += bflo(u.w) * wt; a[7] += bfhi(u.w) * wt;
  };

  #pragma unroll
  for (int r = 0; r < RREL; r++){
    int ob = valid ? (n * 4 + r) : 0;
    int beg = iclamp(offs[ob], 0, N_EDGES);
    int end = iclamp(offs[ob + 1], beg, N_EDGES);
    if (!valid){ beg = 0; end = 0; }
    int cnt = end - beg;
    float winv = (cnt > 0) ? 1.0f / (float)cnt : 0.0f;

    float ac[32];
    #pragma unroll
    for (int j = 0; j < 32; j++) ac[j] = 0.f;

    for (int i = beg; i < end; i += 4){
      int j1 = (i + 1 < end) ? i + 1 : i;
      int j2 = (i + 2 < end) ? i + 2 : i;
      int j3 = (i + 3 < end) ? i + 3 : i;
      int s0 = ssrc[i], s1 = ssrc[j1], s2 = ssrc[j2], s3 = ssrc[j3];
      float wv1 = (i + 1 < end) ? winv : 0.f;
      float wv2 = (i + 2 < end) ? winv : 0.f;
      float wv3 = (i + 3 < end) ? winv : 0.f;
      const uint4* r0 = (const uint4*)(hin + (size_t)s0 * 64 + quad * 4);
      const uint4* r1 = (const uint4*)(hin + (size_t)s1 * 64 + quad * 4);
      const uint4* r2 = (const uint4*)(hin + (size_t)s2 * 64 + quad * 4);
      const uint4* r3 = (const uint4*)(hin + (size_t)s3 * 64 + quad * 4);
      uint4 a00 = r0[0], a01 = r0[4], a02 = r0[8], a03 = r0[12];   // 16 independent
      uint4 a10 = r1[0], a11 = r1[4], a12 = r1[8], a13 = r1[12];   // gathers in flight
      uint4 a20 = r2[0], a21 = r2[4], a22 = r2[8], a23 = r2[12];
      uint4 a30 = r3[0], a31 = r3[4], a32 = r3[8], a33 = r3[12];
      acc8(ac +  0, a00, winv); acc8(ac +  8, a01, winv); acc8(ac + 16, a02, winv); acc8(ac + 24, a03, winv);
      acc8(ac +  0, a10, wv1);  acc8(ac +  8, a11, wv1);  acc8(ac + 16, a12, wv1);  acc8(ac + 24, a13, wv1);
      acc8(ac +  0, a20, wv2);  acc8(ac +  8, a21, wv2);  acc8(ac + 16, a22, wv2);  acc8(ac + 24, a23, wv2);
      acc8(ac +  0, a30, wv3);  acc8(ac +  8, a31, wv3);  acc8(ac + 16, a32, wv3);  acc8(ac + 24, a33, wv3);
    }

    if (!HEAD){
      // 4 MFMA K-steps for this relation; ac already holds the mean
      #pragma unroll
      for (int s = 0; s < 4; s++){
        uint4 pv;
        pv.x = f2bf(ac[s * 8 + 0]) | (f2bf(ac[s * 8 + 1]) << 16);
        pv.y = f2bf(ac[s * 8 + 2]) | (f2bf(ac[s * 8 + 3]) << 16);
        pv.z = f2bf(ac[s * 8 + 4]) | (f2bf(ac[s * 8 + 5]) << 16);
        pv.w = f2bf(ac[s * 8 + 6]) | (f2bf(ac[s * 8 + 7]) << 16);
        bf16x8 af = __builtin_bit_cast(bf16x8, pv);
        const __bf16* bbase = Bt + r * 128 + s * 32 + quad * 8;
        #pragma unroll
        for (int tc = 0; tc < 8; tc++){
          bf16x8 bfr = *(const bf16x8*)(bbase + (size_t)(tc * 16 + l15) * KDIM);
          accC[tc] = __builtin_amdgcn_mfma_f32_16x16x32_bf16(af, bfr, accC[tc], 0, 0, 0);
        }
      }
    } else {
      // per-lane partial dot: lane dim (local t=m*8+u) is k = r*128 + m*32 + quad*8 + u
      #pragma unroll
      for (int m = 0; m < 4; m++){
        #pragma unroll
        for (int u = 0; u < 8; u++){
          float2 wv = *(const float2*)(W3f + 2 * (r * 128 + m * 32 + quad * 8 + u));
          dA += ac[m * 8 + u] * wv.x;
          dB += ac[m * 8 + u] * wv.y;
        }
      }
    }
  }

  if (!HEAD){
    // epilogue: tanh, store bf16. C layout: col=l15, row=quad*4+reg
    #pragma unroll
    for (int tc = 0; tc < 8; tc++){
      #pragma unroll
      for (int reg = 0; reg < 4; reg++){
        int n2 = n0w + quad * 4 + reg;
        if (n2 < N_NODES){
          float v = tanhf(accC[tc][reg]);
          hout[(size_t)n2 * 128 + tc * 16 + l15] = (unsigned short)f2bf(v);
        }
      }
    }
  } else {
    // reduce partial dots across the 4 quads (same l15)
    dA += __shfl_xor(dA, 16); dB += __shfl_xor(dB, 16);
    dA += __shfl_xor(dA, 32); dB += __shfl_xor(dB, 32);
    if (lane < 16 && valid){
      float mx = fmaxf(dA, dB);
      float ea = __expf(dA - mx), eb = __expf(dB - mx);
      float invs = 1.0f / (ea + eb);
      *(float2*)(fout + 2 * n) = (float2){ea * invs, eb * invs};            // softmax [N,2]
      *(float2*)(fout + 2 * N_NODES + 2 * n) = (float2){dA, dB};            // logits  [N,2]
    }
  }
}

// ---------------- launch ----------------

extern "C" void kernel_launch(void* const* d_in, const int* in_sizes, int n_in,
                              void* d_out, int out_size, void* d_ws, size_t ws_size,
                              hipStream_t stream){
  const float* x  = (const float*)d_in[0];
  const int* ei   = (const int*)d_in[1];
  const int* et   = (const int*)d_in[2];
  const float* W1 = (const float*)d_in[3];
  const float* W2 = (const float*)d_in[4];
  const float* W3 = (const float*)d_in[5];
  float* out = (float*)d_out;
  const int* src = ei;
  const int* dst = ei + N_EDGES;

  // workspace layout: ~61 MB total
  char* p = (char*)d_ws;
  auto alloc = [&](size_t bytes) -> char* {
    char* q = p; p += (bytes + 63) & ~(size_t)63; return q;
  };
  int* counts = (int*)alloc((size_t)NKEY * 4);          // reused as cursor
  int* cursor = counts;
  int* offs   = (int*)alloc((size_t)(NKEY + 1) * 4);
  int* bsums  = (int*)alloc(1024 * 4);
  int* ssrc   = (int*)alloc((size_t)N_EDGES * 4);
  unsigned short* Bt = (unsigned short*)alloc((size_t)DDIM * KDIM * 2);
  unsigned short* h1 = (unsigned short*)alloc((size_t)N_NODES * DDIM * 2);
  unsigned short* h2 = (unsigned short*)alloc((size_t)N_NODES * DDIM * 2);
  unsigned* xb = (unsigned*)h2;   // x-as-bf16 lives in h2's slot (dead until layer-2 output)

  // sort edges by (dst, relation)
  hipMemsetAsync(counts, 0, (size_t)NKEY * 4, stream);
  hist_kernel<<<N_EDGES / 256, 256, 0, stream>>>(dst, et, counts);
  int nb = (NKEY + 1023) / 1024;  // 391
  scan_local<<<nb, 1024, 0, stream>>>(counts, offs, bsums, NKEY);
  scan_sums<<<1, 1024, 0, stream>>>(bsums, nb);
  scan_add<<<nb, 1024, 0, stream>>>(offs, cursor, bsums, NKEY, N_EDGES);
  scatter_kernel<<<N_EDGES / 256, 256, 0, stream>>>(src, dst, et, cursor, ssrc);

  int fgrid = (N_NODES + 63) / 64;  // 1563

  // layer 1: x -> packed bf16, agg -> @W1 -> tanh -> h1
  convert_x<<<(N_NODES * 64) / 256, 256, 0, stream>>>(x, xb);
  transpose_w<<<(DDIM * KDIM) / 256, 256, 0, stream>>>(W1, Bt);
  fused_node<0><<<fgrid, 256, 0, stream>>>(xb, ssrc, offs, (const __bf16*)Bt, nullptr, h1, nullptr);
  // layer 2: h1 -> h2 (xb dead from here on)
  transpose_w<<<(DDIM * KDIM) / 256, 256, 0, stream>>>(W2, Bt);
  fused_node<0><<<fgrid, 256, 0, stream>>>((const unsigned*)h1, ssrc, offs, (const __bf16*)Bt, nullptr, h2, nullptr);
  // layer 3 + softmax head (f32 out)
  fused_node<1><<<fgrid, 256, 0, stream>>>((const unsigned*)h2, ssrc, offs, nullptr, W3, nullptr, out);
}

// Round 9
// 838.273 us; speedup vs baseline: 4.1850x; 1.2553x over previous
//
#include <hip/hip_runtime.h>
#include <math.h>

#define N_NODES 100000
#define N_EDGES 1600000
#define RREL 4
#define DDIM 128
#define KDIM 512      // RREL*DDIM
#define NKEY 400000   // N_NODES*RREL

typedef __bf16 bf16x8 __attribute__((ext_vector_type(8)));
typedef float f32x4 __attribute__((ext_vector_type(4)));

__device__ __forceinline__ float bflo(unsigned u){ return __builtin_bit_cast(float, u << 16); }
__device__ __forceinline__ float bfhi(unsigned u){ return __builtin_bit_cast(float, u & 0xffff0000u); }
__device__ __forceinline__ unsigned f2bf(float f){
  unsigned u = __builtin_bit_cast(unsigned, f);
  return (u + 0x7fffu + ((u >> 16) & 1u)) >> 16;   // RNE, finite inputs
}
__device__ __forceinline__ int iclamp(int v, int lo, int hi){
  return v < lo ? lo : (v > hi ? hi : v);
}

// constant-index accumulate: NEVER pass &ac[...] anywhere (SROA must promote to regs)
#define ACC8(B, U, WT) \
  ac[B+0] += bflo(U.x) * WT; ac[B+1] += bfhi(U.x) * WT; \
  ac[B+2] += bflo(U.y) * WT; ac[B+3] += bfhi(U.y) * WT; \
  ac[B+4] += bflo(U.z) * WT; ac[B+5] += bfhi(U.z) * WT; \
  ac[B+6] += bflo(U.w) * WT; ac[B+7] += bfhi(U.w) * WT;

// ---------------- counting sort of edges by key = dst*4 + et ----------------

__global__ void hist_kernel(const int* __restrict__ dst, const int* __restrict__ et,
                            int* __restrict__ counts){
  int e = blockIdx.x * 256 + threadIdx.x;
  int key = iclamp(dst[e] * RREL + et[e], 0, NKEY - 1);
  atomicAdd(&counts[key], 1);
}

__global__ void scan_local(const int* __restrict__ in, int* __restrict__ out,
                           int* __restrict__ bsums, int K){
  __shared__ int s[1024];
  int t = threadIdx.x;
  int i = blockIdx.x * 1024 + t;
  int v = (i < K) ? in[i] : 0;
  s[t] = v; __syncthreads();
  for (int off = 1; off < 1024; off <<= 1){
    int x = (t >= off) ? s[t - off] : 0;
    __syncthreads();
    s[t] += x;
    __syncthreads();
  }
  if (i < K) out[i] = s[t] - v;           // exclusive within block
  if (t == 1023) bsums[blockIdx.x] = s[t];
}

__global__ void scan_sums(int* __restrict__ b, int nb){
  __shared__ int s[1024];
  int t = threadIdx.x;
  int v = (t < nb) ? b[t] : 0;
  s[t] = v; __syncthreads();
  for (int off = 1; off < 1024; off <<= 1){
    int x = (t >= off) ? s[t - off] : 0;
    __syncthreads();
    s[t] += x;
    __syncthreads();
  }
  if (t < nb) b[t] = s[t] - v;            // exclusive block prefix
}

__global__ void scan_add(int* __restrict__ out, int* __restrict__ cursor,
                         const int* __restrict__ bsums, int K, int total){
  int t = threadIdx.x;
  int i = blockIdx.x * 1024 + t;
  if (i < K){
    int v = out[i] + bsums[blockIdx.x];
    out[i] = v;
    cursor[i] = v;
  }
  if (i == 0) out[K] = total;
}

__global__ void scatter_kernel(const int* __restrict__ src, const int* __restrict__ dst,
                               const int* __restrict__ et, int* __restrict__ cursor,
                               int* __restrict__ ssrc){
  int e = blockIdx.x * 256 + threadIdx.x;
  int key = iclamp(dst[e] * RREL + et[e], 0, NKEY - 1);
  int p = atomicAdd(&cursor[key], 1);
  p = iclamp(p, 0, N_EDGES - 1);
  ssrc[p] = iclamp(src[e], 0, N_NODES - 1);
}

// ---------------- x (f32 [N,128]) -> packed bf16 pairs [N,64] uints ----------------

__global__ void convert_x(const float* __restrict__ x, unsigned* __restrict__ xb){
  int i = blockIdx.x * 256 + threadIdx.x;      // over N*64
  float2 v = *(const float2*)(x + (size_t)i * 2);
  xb[i] = f2bf(v.x) | (f2bf(v.y) << 16);
}

// ---------------- W (f32 [512][128]) -> Bt bf16 [128][512] ----------------

__global__ void transpose_w(const float* __restrict__ W, unsigned short* __restrict__ Bt){
  int idx = blockIdx.x * 256 + threadIdx.x;    // 65536
  int k = idx >> 7, n = idx & 127;
  Bt[n * KDIM + k] = (unsigned short)f2bf(W[idx]);
}

// ---------------- fused node kernel: mean -> (@W,tanh | W3-dot,softmax) ----------------
// Wave = 16 nodes; lane (l15,quad) owns node n0+l15, dims quad*8+j of each 32-K window.
// 2-edge unroll: 8 independent uint4 gathers in flight per round; branchless tail
// (duplicate address, weight 0 -> MSHR merge). Mean scale folded into accumulate FMA.
// HEAD=0: 4 MFMA K-steps per relation into accC, tanh epilogue, bf16 store.
// HEAD=1: per-lane dot with W3 dims, quad shfl-reduce, softmax, f32 store.

template<int HEAD>
__global__ __launch_bounds__(256) void fused_node(const unsigned* __restrict__ hin,
                                                  const int* __restrict__ ssrc,
                                                  const int* __restrict__ offs,
                                                  const __bf16* __restrict__ Bt,
                                                  const float* __restrict__ W3f,
                                                  unsigned short* __restrict__ hout,
                                                  float* __restrict__ fout){
  int tid = threadIdx.x;
  int w = tid >> 6, lane = tid & 63;
  int l15 = lane & 15, quad = lane >> 4;
  int n0w = blockIdx.x * 64 + w * 16;
  int n = n0w + l15;                     // this lane's node
  int valid = (n < N_NODES);

  f32x4 accC[8];
  if (!HEAD){
    #pragma unroll
    for (int tc = 0; tc < 8; tc++) accC[tc] = (f32x4){0.f, 0.f, 0.f, 0.f};
  }
  float dA = 0.f, dB = 0.f;

  #pragma unroll
  for (int r = 0; r < RREL; r++){
    int ob = valid ? (n * 4 + r) : 0;
    int beg = iclamp(offs[ob], 0, N_EDGES);
    int end = iclamp(offs[ob + 1], beg, N_EDGES);
    if (!valid){ beg = 0; end = 0; }
    int cnt = end - beg;
    float winv = (cnt > 0) ? 1.0f / (float)cnt : 0.0f;

    float ac[32];
    #pragma unroll
    for (int j = 0; j < 32; j++) ac[j] = 0.f;

    for (int i = beg; i < end; i += 2){
      int j1 = (i + 1 < end) ? i + 1 : i;
      float wv1 = (i + 1 < end) ? winv : 0.f;
      int s0 = ssrc[i], s1 = ssrc[j1];
      const uint4* r0 = (const uint4*)(hin + (size_t)s0 * 64 + quad * 4);
      const uint4* r1 = (const uint4*)(hin + (size_t)s1 * 64 + quad * 4);
      uint4 a00 = r0[0], a01 = r0[4], a02 = r0[8], a03 = r0[12];   // 8 independent
      uint4 a10 = r1[0], a11 = r1[4], a12 = r1[8], a13 = r1[12];   // gathers in flight
      ACC8( 0, a00, winv); ACC8( 8, a01, winv); ACC8(16, a02, winv); ACC8(24, a03, winv);
      ACC8( 0, a10, wv1);  ACC8( 8, a11, wv1);  ACC8(16, a12, wv1);  ACC8(24, a13, wv1);
    }

    if (!HEAD){
      // 4 MFMA K-steps for this relation; ac already holds the mean
      #pragma unroll
      for (int s = 0; s < 4; s++){
        uint4 pv;
        pv.x = f2bf(ac[s * 8 + 0]) | (f2bf(ac[s * 8 + 1]) << 16);
        pv.y = f2bf(ac[s * 8 + 2]) | (f2bf(ac[s * 8 + 3]) << 16);
        pv.z = f2bf(ac[s * 8 + 4]) | (f2bf(ac[s * 8 + 5]) << 16);
        pv.w = f2bf(ac[s * 8 + 6]) | (f2bf(ac[s * 8 + 7]) << 16);
        bf16x8 af = __builtin_bit_cast(bf16x8, pv);
        const __bf16* bbase = Bt + r * 128 + s * 32 + quad * 8;
        #pragma unroll
        for (int tc = 0; tc < 8; tc++){
          bf16x8 bfr = *(const bf16x8*)(bbase + (size_t)(tc * 16 + l15) * KDIM);
          accC[tc] = __builtin_amdgcn_mfma_f32_16x16x32_bf16(af, bfr, accC[tc], 0, 0, 0);
        }
      }
    } else {
      // per-lane partial dot: local dim t=m*8+u is k = r*128 + m*32 + quad*8 + u
      #pragma unroll
      for (int m = 0; m < 4; m++){
        #pragma unroll
        for (int u = 0; u < 8; u++){
          float2 wv = *(const float2*)(W3f + 2 * (r * 128 + m * 32 + quad * 8 + u));
          dA += ac[m * 8 + u] * wv.x;
          dB += ac[m * 8 + u] * wv.y;
        }
      }
    }
  }

  if (!HEAD){
    // epilogue: tanh, store bf16. C layout: col=l15, row=quad*4+reg
    #pragma unroll
    for (int tc = 0; tc < 8; tc++){
      #pragma unroll
      for (int reg = 0; reg < 4; reg++){
        int n2 = n0w + quad * 4 + reg;
        if (n2 < N_NODES){
          float v = tanhf(accC[tc][reg]);
          hout[(size_t)n2 * 128 + tc * 16 + l15] = (unsigned short)f2bf(v);
        }
      }
    }
  } else {
    // reduce partial dots across the 4 quads (same l15)
    dA += __shfl_xor(dA, 16); dB += __shfl_xor(dB, 16);
    dA += __shfl_xor(dA, 32); dB += __shfl_xor(dB, 32);
    if (lane < 16 && valid){
      float mx = fmaxf(dA, dB);
      float ea = __expf(dA - mx), eb = __expf(dB - mx);
      float invs = 1.0f / (ea + eb);
      *(float2*)(fout + 2 * n) = (float2){ea * invs, eb * invs};            // softmax [N,2]
      *(float2*)(fout + 2 * N_NODES + 2 * n) = (float2){dA, dB};            // logits  [N,2]
    }
  }
}

// ---------------- launch ----------------

extern "C" void kernel_launch(void* const* d_in, const int* in_sizes, int n_in,
                              void* d_out, int out_size, void* d_ws, size_t ws_size,
                              hipStream_t stream){
  const float* x  = (const float*)d_in[0];
  const int* ei   = (const int*)d_in[1];
  const int* et   = (const int*)d_in[2];
  const float* W1 = (const float*)d_in[3];
  const float* W2 = (const float*)d_in[4];
  const float* W3 = (const float*)d_in[5];
  float* out = (float*)d_out;
  const int* src = ei;
  const int* dst = ei + N_EDGES;

  // workspace layout: ~61 MB total
  char* p = (char*)d_ws;
  auto alloc = [&](size_t bytes) -> char* {
    char* q = p; p += (bytes + 63) & ~(size_t)63; return q;
  };
  int* counts = (int*)alloc((size_t)NKEY * 4);          // reused as cursor
  int* cursor = counts;
  int* offs   = (int*)alloc((size_t)(NKEY + 1) * 4);
  int* bsums  = (int*)alloc(1024 * 4);
  int* ssrc   = (int*)alloc((size_t)N_EDGES * 4);
  unsigned short* Bt = (unsigned short*)alloc((size_t)DDIM * KDIM * 2);
  unsigned short* h1 = (unsigned short*)alloc((size_t)N_NODES * DDIM * 2);
  unsigned short* h2 = (unsigned short*)alloc((size_t)N_NODES * DDIM * 2);
  unsigned* xb = (unsigned*)h2;   // x-as-bf16 lives in h2's slot (dead until layer-2 output)

  // sort edges by (dst, relation)
  hipMemsetAsync(counts, 0, (size_t)NKEY * 4, stream);
  hist_kernel<<<N_EDGES / 256, 256, 0, stream>>>(dst, et, counts);
  int nb = (NKEY + 1023) / 1024;  // 391
  scan_local<<<nb, 1024, 0, stream>>>(counts, offs, bsums, NKEY);
  scan_sums<<<1, 1024, 0, stream>>>(bsums, nb);
  scan_add<<<nb, 1024, 0, stream>>>(offs, cursor, bsums, NKEY, N_EDGES);
  scatter_kernel<<<N_EDGES / 256, 256, 0, stream>>>(src, dst, et, cursor, ssrc);

  int fgrid = (N_NODES + 63) / 64;  // 1563

  // layer 1: x -> packed bf16, agg -> @W1 -> tanh -> h1
  convert_x<<<(N_NODES * 64) / 256, 256, 0, stream>>>(x, xb);
  transpose_w<<<(DDIM * KDIM) / 256, 256, 0, stream>>>(W1, Bt);
  fused_node<0><<<fgrid, 256, 0, stream>>>(xb, ssrc, offs, (const __bf16*)Bt, nullptr, h1, nullptr);
  // layer 2: h1 -> h2 (xb dead from here on)
  transpose_w<<<(DDIM * KDIM) / 256, 256, 0, stream>>>(W2, Bt);
  fused_node<0><<<fgrid, 256, 0, stream>>>((const unsigned*)h1, ssrc, offs, (const __bf16*)Bt, nullptr, h2, nullptr);
  // layer 3 + softmax head (f32 out)
  fused_node<1><<<fgrid, 256, 0, stream>>>((const unsigned*)h2, ssrc, offs, nullptr, W3, nullptr, out);
}